// Round 14
// baseline (121.226 us; speedup 1.0000x reference)
//
#include <hip/hip_runtime.h>
#include <hip/hip_bf16.h>

// Mamba block: B=4, L=512, D_MODEL=128, D_INNER=D_STATE=256
// 4 launches: [proj MFMA + weight-prep] -> dbc MFMA (64x128 tiles) ->
// scan1 (chunk-local, c<7 only, dbuf prefetch) ->
// scan3 (inline combine + outputs + last-finisher fused out-GEMM)

#define MROWS 2048
#define DM 128
#define DI 256
#define DS 256
#define LLEN 512
#define LC 64
#define NC 8

#define LOG2E 1.44269504088896340736f

typedef short bf16x8 __attribute__((ext_vector_type(8)));
typedef float f32x4  __attribute__((ext_vector_type(4)));

__device__ __forceinline__ short f2bf(float f) {
    union { float f; unsigned u; } v; v.f = f;
    unsigned r = v.u + 0x7FFFu + ((v.u >> 16) & 1u);   // RNE
    return (short)(r >> 16);
}

// Taylor-2 exp(a*dl): |a*dl| <= ~0.04 -> rel err < 1e-5
#define TEXP2(c1, c2, dl) fmaf(fmaf((c2), (dl), (c1)), (dl), 1.f)

// ---------------------------------------------------------------------------
// 32x32 transpose+convert tile (fp32 src -> bf16 dst, dst N-major)
// ---------------------------------------------------------------------------
__device__ __forceinline__ void tconv(float (*tile)[33],
                                      const float* __restrict__ src,
                                      short* __restrict__ dst,
                                      int Ms, int Ns, int ti, int tj, int tid)
{
    const int r = tid >> 5, c = tid & 31;
#pragma unroll
    for (int i = 0; i < 4; ++i)
        tile[r + 8 * i][c] = src[(size_t)(ti * 32 + r + 8 * i) * Ns + tj * 32 + c];
    __syncthreads();
#pragma unroll
    for (int i = 0; i < 4; ++i)
        dst[(size_t)(tj * 32 + r + 8 * i) * Ms + ti * 32 + c] = f2bf(tile[c][r + 8 * i]);
}

// ---------------------------------------------------------------------------
// kernel 1: in_proj (MFMA) + fused weight-prep blocks  (grid 15x32, 256 thr)
// ---------------------------------------------------------------------------
__global__ __launch_bounds__(256) void k_proj_mfma(
    const float* __restrict__ x, const float* __restrict__ W_in,
    const float* __restrict__ Wd, const float* __restrict__ Wb,
    const float* __restrict__ Wc, const float* __restrict__ W_out,
    float* __restrict__ xs, short* __restrict__ xs_bf, float* __restrict__ sz,
    short* __restrict__ WdbcT, short* __restrict__ W_outT)
{
    const int t = threadIdx.x;

    if (blockIdx.x >= 8) {               // ---- prep role: 224 tiles ----
        __shared__ float tile[32][33];
        const int uu = (blockIdx.x - 8) * 32 + blockIdx.y;
        if (uu < 64)       tconv(tile, Wd,    WdbcT,                       256, 256, uu & 7,         uu >> 3,         t);
        else if (uu < 128) tconv(tile, Wb,    WdbcT + (size_t)256 * 256,   256, 256, (uu - 64) & 7,  (uu - 64) >> 3,  t);
        else if (uu < 192) tconv(tile, Wc,    WdbcT + (size_t)512 * 256,   256, 256, (uu - 128) & 7, (uu - 128) >> 3, t);
        else if (uu < 224) tconv(tile, W_out, W_outT,                      256, 128, (uu - 192) & 7, (uu - 192) >> 3, t);
        return;
    }

    // ---- GEMM role ----
    __shared__ short As[64][136];
    __shared__ short Bs[64][136];
    f32x4 acc[4] = {};
    const int w = t >> 6, lane = t & 63;
    const int srow = t >> 2, sseg = t & 3;
    const int frow = lane & 15, fk = (lane >> 4) << 3;
    const int r0 = blockIdx.y * 64, n0 = blockIdx.x * 64;

    {
        const float* ap = x + (size_t)(r0 + srow) * DM + sseg * 32;
        short tmp[32];
#pragma unroll
        for (int j = 0; j < 8; ++j) {
            float4 f = *(const float4*)(ap + j * 4);
            tmp[j * 4 + 0] = f2bf(f.x); tmp[j * 4 + 1] = f2bf(f.y);
            tmp[j * 4 + 2] = f2bf(f.z); tmp[j * 4 + 3] = f2bf(f.w);
        }
#pragma unroll
        for (int m = 0; m < 4; ++m)
            *(bf16x8*)&As[srow][sseg * 32 + m * 8] = *(bf16x8*)&tmp[m * 8];
    }
    {
#pragma unroll
        for (int i = 0; i < 32; i += 2) {
            const int k = sseg * 32 + i;
            float f0 = W_in[(size_t)k * 512 + n0 + srow];
            float f1 = W_in[(size_t)(k + 1) * 512 + n0 + srow];
            unsigned pk = (unsigned short)f2bf(f0) | ((unsigned)(unsigned short)f2bf(f1) << 16);
            *(unsigned*)&Bs[srow][k] = pk;
        }
    }
    __syncthreads();

#pragma unroll
    for (int kk = 0; kk < 128; kk += 32) {
        bf16x8 af = *(const bf16x8*)&As[w * 16 + frow][kk + fk];
#pragma unroll
        for (int ct = 0; ct < 4; ++ct) {
            bf16x8 bfr = *(const bf16x8*)&Bs[ct * 16 + frow][kk + fk];
            acc[ct] = __builtin_amdgcn_mfma_f32_16x16x32_bf16(af, bfr, acc[ct], 0, 0, 0);
        }
    }

    const int rr = r0 + w * 16 + (lane >> 4) * 4;
    const int c0 = n0 + (lane & 15);
#pragma unroll
    for (int ct = 0; ct < 4; ++ct) {
        const int c = c0 + ct * 16;
#pragma unroll
        for (int rg = 0; rg < 4; ++rg) {
            const float v = acc[ct][rg];
            const int r = rr + rg;
            if (c < DI) {
                xs[(size_t)r * DI + c]    = v;
                xs_bf[(size_t)r * DI + c] = f2bf(v);
            } else {
                sz[(size_t)r * DI + (c - DI)] = v / (1.f + __expf(-v));
            }
        }
    }
}

// ---------------------------------------------------------------------------
// kernel 2: dbc GEMM — 192 blocks x 512 thr, tile 64r x 128c, K=256
// ---------------------------------------------------------------------------
__global__ __launch_bounds__(512) void k_dbc(
    const short* __restrict__ xs_bf, const short* __restrict__ WdbcT,
    const float* __restrict__ xs,
    float* __restrict__ dlt, float* __restrict__ u, float* __restrict__ cvv)
{
    __shared__ short As[64][72], Bs[128][72];
    const int blk = blockIdx.x, t = threadIdx.x;
    const int w8 = t >> 6, lane = t & 63;
    const int rf = w8 & 3, ch = w8 >> 2;
    const int frow = lane & 15, fk = (lane >> 4) << 3;
    const int bx = blk % 6, by = blk / 6;
    const int r0 = by * 64, n0 = bx * 128;
    const int arow = t >> 3, ak = (t & 7) * 8;
    const int brow = t >> 2, bk = (t & 3) * 16;
    f32x4 acc[4] = {};

    for (int k0 = 0; k0 < DI; k0 += 64) {
        bf16x8 a0 = *(const bf16x8*)(xs_bf + (size_t)(r0 + arow) * DI + k0 + ak);
        bf16x8 b0 = *(const bf16x8*)(WdbcT + (size_t)(n0 + brow) * DI + k0 + bk);
        bf16x8 b1 = *(const bf16x8*)(WdbcT + (size_t)(n0 + brow) * DI + k0 + bk + 8);
        __syncthreads();
        *(bf16x8*)&As[arow][ak]     = a0;
        *(bf16x8*)&Bs[brow][bk]     = b0;
        *(bf16x8*)&Bs[brow][bk + 8] = b1;
        __syncthreads();
#pragma unroll
        for (int kk = 0; kk < 64; kk += 32) {
            bf16x8 af = *(const bf16x8*)&As[rf * 16 + frow][kk + fk];
#pragma unroll
            for (int ct = 0; ct < 4; ++ct) {
                bf16x8 bfr = *(const bf16x8*)&Bs[(ch * 4 + ct) * 16 + frow][kk + fk];
                acc[ct] = __builtin_amdgcn_mfma_f32_16x16x32_bf16(af, bfr, acc[ct], 0, 0, 0);
            }
        }
    }

    const int rr = r0 + rf * 16 + (lane >> 4) * 4;
    const int nbase = n0 + ch * 64;
    const int wsel = nbase >> 8;          // 0: delta, 1: B, 2: C
    const int nb = nbase & 255;
#pragma unroll
    for (int ct = 0; ct < 4; ++ct) {
        const int c = nb + ct * 16 + (lane & 15);
#pragma unroll
        for (int rg = 0; rg < 4; ++rg) {
            const float v = acc[ct][rg];
            const size_t idx = (size_t)(rr + rg) * DI + c;
            if (wsel == 0)      dlt[idx] = v;
            else if (wsel == 1) u[idx]   = v * xs[idx];   // Bv * xs
            else                cvv[idx] = v;
        }
    }
}

// ---------------------------------------------------------------------------
// kernel 3: scan pass 1 — chunk-local states, 2-deep register dbuf prefetch.
// 448 blocks: chunks 0..6 only (chunk 7's T/dsum are never consumed).
// Blocks 0..31 also zero the finisher counters for this call.
// ---------------------------------------------------------------------------
__global__ __launch_bounds__(256) void k_scan1(
    const float* __restrict__ dlt, const float* __restrict__ u,
    const float* __restrict__ Aa,
    float* __restrict__ tc, float* __restrict__ dsm,
    unsigned* __restrict__ cnt)
{
    const int lane = threadIdx.x & 63;
    const int w    = threadIdx.x >> 6;
    const int blk  = blockIdx.x;
    const int b  = blk & 3;
    const int r  = blk >> 2;          // 0..111
    const int c  = r % 7;             // 0..6
    const int d0 = ((r / 7) * 4 + w) * 4;

    if (blk < 32 && threadIdx.x == 0) cnt[blk] = 0u;   // reset finisher counters

    __shared__ float dls[4][4][LC];
    const size_t base = (size_t)b * LLEN * DI + (size_t)c * LC * DI;

    float4 dv = *(const float4*)(dlt + base + (size_t)lane * DI + d0);
    dls[w][0][lane] = dv.x;
    dls[w][1][lane] = dv.y;
    dls[w][2][lane] = dv.z;
    dls[w][3][lane] = dv.w;
    float dsv[4] = { dv.x, dv.y, dv.z, dv.w };
#pragma unroll
    for (int dd = 0; dd < 4; ++dd) {
#pragma unroll
        for (int off = 32; off > 0; off >>= 1)
            dsv[dd] += __shfl_xor(dsv[dd], off);
    }

    float4 c1[4], c2[4];
#pragma unroll
    for (int dd = 0; dd < 4; ++dd) {
        float4 a = *(const float4*)(Aa + (size_t)(d0 + dd) * DS + lane * 4);
        c1[dd] = a;
        c2[dd] = make_float4(0.5f * a.x * a.x, 0.5f * a.y * a.y,
                             0.5f * a.z * a.z, 0.5f * a.w * a.w);
    }

    const float4* up = (const float4*)(u + base) + lane;
    float4 s[4] = {};
    float4 uA[4], uB[4];

#define S1_PRE(UB, G)                                                         \
    {                                                                         \
        _Pragma("unroll")                                                     \
        for (int i = 0; i < 4; ++i)                                           \
            UB[i] = up[(size_t)((G) * 4 + i) * 64];                           \
    }

#define S1_COMP(UB, G)                                                        \
    {                                                                         \
        _Pragma("unroll")                                                     \
        for (int i = 0; i < 4; ++i) {                                         \
            const int l = (G) * 4 + i;                                        \
            _Pragma("unroll")                                                 \
            for (int dd = 0; dd < 4; ++dd) {                                  \
                const float dl = dls[w][dd][l];                               \
                s[dd].x = fmaf(TEXP2(c1[dd].x, c2[dd].x, dl), s[dd].x, dl * UB[i].x); \
                s[dd].y = fmaf(TEXP2(c1[dd].y, c2[dd].y, dl), s[dd].y, dl * UB[i].y); \
                s[dd].z = fmaf(TEXP2(c1[dd].z, c2[dd].z, dl), s[dd].z, dl * UB[i].z); \
                s[dd].w = fmaf(TEXP2(c1[dd].w, c2[dd].w, dl), s[dd].w, dl * UB[i].w); \
            }                                                                 \
        }                                                                     \
    }

    S1_PRE(uA, 0)
    for (int g2 = 0; g2 < 8; ++g2) {
        S1_PRE(uB, g2 * 2 + 1)
        S1_COMP(uA, g2 * 2)
        if (g2 < 7) S1_PRE(uA, g2 * 2 + 2)
        S1_COMP(uB, g2 * 2 + 1)
    }
#undef S1_PRE
#undef S1_COMP

    const size_t rbb = ((size_t)(b * 256 + d0)) * NC + c;
#pragma unroll
    for (int dd = 0; dd < 4; ++dd) {
        *(float4*)(tc + (rbb + (size_t)dd * NC) * 256 + lane * 4) = s[dd];
        if (lane == 0) dsm[rbb + dd * NC] = dsv[dd];
    }
}

// ---------------------------------------------------------------------------
// kernel 4: scan pass 3 — inline chunk-combine prologue + outputs +
// last-finisher fused out GEMM. 512 blocks; the 16th block to finish a
// (b,c) chunk computes out[rows of chunk] = (yv . sz) @ W_out.
// ---------------------------------------------------------------------------
__global__ __launch_bounds__(256) void k_scan3(
    const float* __restrict__ dlt, const float* __restrict__ u,
    const float* __restrict__ cvv, const float* __restrict__ Aa,
    const float* __restrict__ tc, const float* __restrict__ dsm,
    float* __restrict__ yv,
    const float* __restrict__ szp, const short* __restrict__ W_outT,
    float* __restrict__ out, unsigned* __restrict__ cnt)
{
    const int lane = threadIdx.x & 63;
    const int w    = threadIdx.x >> 6;
    const int blk  = blockIdx.x;
    const int b  = blk & 3;
    const int c  = (blk >> 2) & 7;
    const int d0 = ((blk >> 5) * 4 + w) * 4;

    __shared__ float dls[4][4][LC];
    __shared__ float T[4][LC][20];      // stride 20 floats = 80B (16B aligned)
    __shared__ bool  lastf;

    const size_t base = (size_t)b * LLEN * DI + (size_t)c * LC * DI;

    float4 dv = *(const float4*)(dlt + base + (size_t)lane * DI + d0);
    dls[w][0][lane] = dv.x;
    dls[w][1][lane] = dv.y;
    dls[w][2][lane] = dv.z;
    dls[w][3][lane] = dv.w;

    float4 c1[4], c2[4];
#pragma unroll
    for (int dd = 0; dd < 4; ++dd) {
        float4 a = *(const float4*)(Aa + (size_t)(d0 + dd) * DS + lane * 4);
        c1[dd] = a;
        c2[dd] = make_float4(0.5f * a.x * a.x, 0.5f * a.y * a.y,
                             0.5f * a.z * a.z, 0.5f * a.w * a.w);
    }

    // ---- inline combine: s = s_init[c] from chunks 0..c-1 ----
    float4 s[4] = {};
    for (int cc = 0; cc < c; ++cc) {
#pragma unroll
        for (int dd = 0; dd < 4; ++dd) {
            const size_t rbd = ((size_t)(b * 256 + d0 + dd)) * NC + cc;
            const float4 Tt = *(const float4*)(tc + rbd * 256 + lane * 4);
            const float  Dc = dsm[rbd] * LOG2E;
            s[dd].x = exp2f(c1[dd].x * Dc) * s[dd].x + Tt.x;
            s[dd].y = exp2f(c1[dd].y * Dc) * s[dd].y + Tt.y;
            s[dd].z = exp2f(c1[dd].z * Dc) * s[dd].z + Tt.z;
            s[dd].w = exp2f(c1[dd].w * Dc) * s[dd].w + Tt.w;
        }
    }

    const float4* up = (const float4*)(u + base) + lane;
    const float4* cp = (const float4*)(cvv + base) + lane;
    float* yb = yv + base;

    const int col = lane & 15, seg = lane >> 4;
    float4 uA[4], cA[4], uB[4], cB[4];

#define S3_PRE(UB, CB, G)                                                     \
    {                                                                         \
        _Pragma("unroll")                                                     \
        for (int i = 0; i < 4; ++i) {                                         \
            UB[i] = up[(size_t)((G) * 4 + i) * 64];                           \
            CB[i] = cp[(size_t)((G) * 4 + i) * 64];                           \
        }                                                                     \
    }

#define S3_COMP(UB, CB, G)                                                    \
    {                                                                         \
        f32x4 pacc[4];                                                        \
        _Pragma("unroll")                                                     \
        for (int i = 0; i < 4; ++i) {                                         \
            const int l = (G) * 4 + i;                                        \
            _Pragma("unroll")                                                 \
            for (int dd = 0; dd < 4; ++dd) {                                  \
                const float dl = dls[w][dd][l];                               \
                s[dd].x = fmaf(TEXP2(c1[dd].x, c2[dd].x, dl), s[dd].x, dl * UB[i].x); \
                s[dd].y = fmaf(TEXP2(c1[dd].y, c2[dd].y, dl), s[dd].y, dl * UB[i].y); \
                s[dd].z = fmaf(TEXP2(c1[dd].z, c2[dd].z, dl), s[dd].z, dl * UB[i].z); \
                s[dd].w = fmaf(TEXP2(c1[dd].w, c2[dd].w, dl), s[dd].w, dl * UB[i].w); \
                pacc[dd][i] =                                                 \
                    fmaf(s[dd].w, CB[i].w, fmaf(s[dd].z, CB[i].z,             \
                         fmaf(s[dd].y, CB[i].y, s[dd].x * CB[i].x)));         \
            }                                                                 \
        }                                                                     \
        _Pragma("unroll")                                                     \
        for (int dd = 0; dd < 4; ++dd)                                        \
            *(f32x4*)&T[w][lane][dd * 4] = pacc[dd];                          \
        float sm = 0.f;                                                       \
        _Pragma("unroll")                                                     \
        for (int r = 0; r < 16; ++r)                                          \
            sm += T[w][seg * 16 + r][col];                                    \
        sm += __shfl_xor(sm, 16);                                             \
        sm += __shfl_xor(sm, 32);                                             \
        if (lane < 16)                                                        \
            yb[(size_t)((G) * 4 + (col & 3)) * DI + d0 + (col >> 2)] = sm;    \
    }

    S3_PRE(uA, cA, 0)
    for (int g2 = 0; g2 < 8; ++g2) {
        S3_PRE(uB, cB, g2 * 2 + 1)
        S3_COMP(uA, cA, g2 * 2)
        if (g2 < 7) S3_PRE(uA, cA, g2 * 2 + 2)
        S3_COMP(uB, cB, g2 * 2 + 1)
    }
#undef S3_PRE
#undef S3_COMP

    // ---- last-finisher: fused out GEMM for this chunk's 64 rows ----
    __threadfence();                          // make our yv writes visible
    if (threadIdx.x == 0)
        lastf = (atomicAdd(&cnt[b * 8 + c], 1u) == 15u);
    __syncthreads();
    if (!lastf) return;
    __threadfence();                          // see all 16 blocks' yv writes

    // overlay GEMM tiles onto T storage (18432B <= 20480B)
    short (*As)[72] = reinterpret_cast<short(*)[72]>(&T[0][0][0]);
    short (*Bs)[72] = reinterpret_cast<short(*)[72]>(&T[0][0][0]) + 64;
    const int r0f = b * 512 + c * 64;         // row base of this chunk
    const int t   = threadIdx.x;
    const int ww  = t >> 6, ln = t & 63;
    const int srow = t >> 2, sseg = t & 3;
    const int frow = ln & 15, fk = (ln >> 4) << 3;

    for (int half = 0; half < 2; ++half) {
        const int n0 = half * 64;
        f32x4 acc[4] = {};
        for (int k0 = 0; k0 < DI; k0 += 64) {
            const size_t aoff = (size_t)(r0f + srow) * DI + k0 + sseg * 16;
            float4 y0 = *(const float4*)(yv + aoff);
            float4 y1 = *(const float4*)(yv + aoff + 4);
            float4 y2 = *(const float4*)(yv + aoff + 8);
            float4 y3 = *(const float4*)(yv + aoff + 12);
            float4 s0 = *(const float4*)(szp + aoff);
            float4 s1 = *(const float4*)(szp + aoff + 4);
            float4 s2 = *(const float4*)(szp + aoff + 8);
            float4 s3 = *(const float4*)(szp + aoff + 12);
            const short* bg = W_outT + (size_t)(n0 + srow) * DI + k0 + sseg * 16;
            bf16x8 b0 = *(const bf16x8*)bg;
            bf16x8 b1 = *(const bf16x8*)(bg + 8);
            bf16x8 a0, a1;
            a0[0] = f2bf(y0.x * s0.x); a0[1] = f2bf(y0.y * s0.y);
            a0[2] = f2bf(y0.z * s0.z); a0[3] = f2bf(y0.w * s0.w);
            a0[4] = f2bf(y1.x * s1.x); a0[5] = f2bf(y1.y * s1.y);
            a0[6] = f2bf(y1.z * s1.z); a0[7] = f2bf(y1.w * s1.w);
            a1[0] = f2bf(y2.x * s2.x); a1[1] = f2bf(y2.y * s2.y);
            a1[2] = f2bf(y2.z * s2.z); a1[3] = f2bf(y2.w * s2.w);
            a1[4] = f2bf(y3.x * s3.x); a1[5] = f2bf(y3.y * s3.y);
            a1[6] = f2bf(y3.z * s3.z); a1[7] = f2bf(y3.w * s3.w);
            __syncthreads();
            *(bf16x8*)&As[srow][sseg * 16]     = a0;
            *(bf16x8*)&As[srow][sseg * 16 + 8] = a1;
            *(bf16x8*)&Bs[srow][sseg * 16]     = b0;
            *(bf16x8*)&Bs[srow][sseg * 16 + 8] = b1;
            __syncthreads();
#pragma unroll
            for (int kk = 0; kk < 64; kk += 32) {
                bf16x8 af = *(const bf16x8*)&As[ww * 16 + frow][kk + fk];
#pragma unroll
                for (int ct = 0; ct < 4; ++ct) {
                    bf16x8 bfr = *(const bf16x8*)&Bs[ct * 16 + frow][kk + fk];
                    acc[ct] = __builtin_amdgcn_mfma_f32_16x16x32_bf16(af, bfr, acc[ct], 0, 0, 0);
                }
            }
        }
        const int rr = r0f + ww * 16 + (ln >> 4) * 4;
        const int c0 = n0 + (ln & 15);
#pragma unroll
        for (int ct = 0; ct < 4; ++ct) {
            const int cc = c0 + ct * 16;
#pragma unroll
            for (int rg = 0; rg < 4; ++rg)
                out[(size_t)(rr + rg) * DM + cc] = acc[ct][rg];
        }
        __syncthreads();   // before next half reuses As/Bs
    }
}

// ---------------------------------------------------------------------------
extern "C" void kernel_launch(void* const* d_in, const int* in_sizes, int n_in,
                              void* d_out, int out_size, void* d_ws, size_t ws_size,
                              hipStream_t stream)
{
    const float* x       = (const float*)d_in[0];
    const float* W_in    = (const float*)d_in[1];
    const float* W_delta = (const float*)d_in[2];
    const float* W_B     = (const float*)d_in[3];
    const float* W_C     = (const float*)d_in[4];
    const float* W_out   = (const float*)d_in[5];
    const float* A       = (const float*)d_in[6];
    // d_in[7] = D, unused by the reference scan

    float* out = (float*)d_out;
    float* ws  = (float*)d_ws;

    const size_t S = (size_t)MROWS * DI;   // 524288 floats per plane (2 MB)
    float* xs  = ws;
    float* sz  = ws + S;
    float* dlt = ws + 2 * S;
    float* u   = ws + 3 * S;
    float* cv  = ws + 4 * S;
    float* yv  = ws + 5 * S;
    float* tc  = ws + 6 * S;                              // 1024*8*256 = 8 MB
    float* dsm = tc + (size_t)1024 * NC * 256;            // 8192 floats

    short* xs_bf  = (short*)(dsm + (size_t)1024 * NC);    // 2048*256
    short* WdbcT  = xs_bf + (size_t)MROWS * DI;           // 768*256
    short* W_outT = WdbcT + (size_t)768 * DI;             // 128*256
    unsigned* cnt = (unsigned*)(W_outT + (size_t)128 * DI); // 32 counters

    k_proj_mfma<<<dim3(15, 32), 256, 0, stream>>>(x, W_in, W_delta, W_B, W_C, W_out,
                                                  xs, xs_bf, sz, WdbcT, W_outT);
    k_dbc      <<<dim3(192), 512, 0, stream>>>(xs_bf, WdbcT, xs, dlt, u, cv);
    k_scan1    <<<dim3(448), 256, 0, stream>>>(dlt, u, A, tc, dsm, cnt);
    k_scan3    <<<dim3(512), 256, 0, stream>>>(dlt, u, cv, A, tc, dsm, yv,
                                               sz, W_outT, out, cnt);
}

// Round 15
// 69.278 us; speedup vs baseline: 1.7498x; 1.7498x over previous
//
#include <hip/hip_runtime.h>
#include <hip/hip_bf16.h>

// Mamba block: B=4, L=512, D_MODEL=128, D_INNER=D_STATE=256
// 5 launches: [proj MFMA + weight-prep] -> dbc MFMA (64x128 tiles) ->
// scan1 (chunk-local, chunks 0..6 only, dbuf prefetch) ->
// scan3 (inline combine + outputs, dbuf prefetch, conflict-free T) -> out MFMA

#define MROWS 2048
#define DM 128
#define DI 256
#define DS 256
#define LLEN 512
#define LC 64
#define NC 8

#define LOG2E 1.44269504088896340736f

typedef short bf16x8 __attribute__((ext_vector_type(8)));
typedef float f32x4  __attribute__((ext_vector_type(4)));

__device__ __forceinline__ short f2bf(float f) {
    union { float f; unsigned u; } v; v.f = f;
    unsigned r = v.u + 0x7FFFu + ((v.u >> 16) & 1u);   // RNE
    return (short)(r >> 16);
}

// Taylor-2 exp(a*dl): |a*dl| <= ~0.04 -> rel err < 1e-5
#define TEXP2(c1, c2, dl) fmaf(fmaf((c2), (dl), (c1)), (dl), 1.f)

// ---------------------------------------------------------------------------
// 32x32 transpose+convert tile (fp32 src -> bf16 dst, dst N-major)
// ---------------------------------------------------------------------------
__device__ __forceinline__ void tconv(float (*tile)[33],
                                      const float* __restrict__ src,
                                      short* __restrict__ dst,
                                      int Ms, int Ns, int ti, int tj, int tid)
{
    const int r = tid >> 5, c = tid & 31;
#pragma unroll
    for (int i = 0; i < 4; ++i)
        tile[r + 8 * i][c] = src[(size_t)(ti * 32 + r + 8 * i) * Ns + tj * 32 + c];
    __syncthreads();
#pragma unroll
    for (int i = 0; i < 4; ++i)
        dst[(size_t)(tj * 32 + r + 8 * i) * Ms + ti * 32 + c] = f2bf(tile[c][r + 8 * i]);
}

// ---------------------------------------------------------------------------
// kernel 1: in_proj (MFMA) + fused weight-prep blocks  (grid 15x32, 256 thr)
// ---------------------------------------------------------------------------
__global__ __launch_bounds__(256) void k_proj_mfma(
    const float* __restrict__ x, const float* __restrict__ W_in,
    const float* __restrict__ Wd, const float* __restrict__ Wb,
    const float* __restrict__ Wc, const float* __restrict__ W_out,
    float* __restrict__ xs, short* __restrict__ xs_bf, float* __restrict__ sz,
    short* __restrict__ WdbcT, short* __restrict__ W_outT)
{
    const int t = threadIdx.x;

    if (blockIdx.x >= 8) {               // ---- prep role: 224 tiles ----
        __shared__ float tile[32][33];
        const int uu = (blockIdx.x - 8) * 32 + blockIdx.y;
        if (uu < 64)       tconv(tile, Wd,    WdbcT,                       256, 256, uu & 7,         uu >> 3,         t);
        else if (uu < 128) tconv(tile, Wb,    WdbcT + (size_t)256 * 256,   256, 256, (uu - 64) & 7,  (uu - 64) >> 3,  t);
        else if (uu < 192) tconv(tile, Wc,    WdbcT + (size_t)512 * 256,   256, 256, (uu - 128) & 7, (uu - 128) >> 3, t);
        else if (uu < 224) tconv(tile, W_out, W_outT,                      256, 128, (uu - 192) & 7, (uu - 192) >> 3, t);
        return;
    }

    // ---- GEMM role ----
    __shared__ short As[64][136];
    __shared__ short Bs[64][136];
    f32x4 acc[4] = {};
    const int w = t >> 6, lane = t & 63;
    const int srow = t >> 2, sseg = t & 3;
    const int frow = lane & 15, fk = (lane >> 4) << 3;
    const int r0 = blockIdx.y * 64, n0 = blockIdx.x * 64;

    {
        const float* ap = x + (size_t)(r0 + srow) * DM + sseg * 32;
        short tmp[32];
#pragma unroll
        for (int j = 0; j < 8; ++j) {
            float4 f = *(const float4*)(ap + j * 4);
            tmp[j * 4 + 0] = f2bf(f.x); tmp[j * 4 + 1] = f2bf(f.y);
            tmp[j * 4 + 2] = f2bf(f.z); tmp[j * 4 + 3] = f2bf(f.w);
        }
#pragma unroll
        for (int m = 0; m < 4; ++m)
            *(bf16x8*)&As[srow][sseg * 32 + m * 8] = *(bf16x8*)&tmp[m * 8];
    }
    {
#pragma unroll
        for (int i = 0; i < 32; i += 2) {
            const int k = sseg * 32 + i;
            float f0 = W_in[(size_t)k * 512 + n0 + srow];
            float f1 = W_in[(size_t)(k + 1) * 512 + n0 + srow];
            unsigned pk = (unsigned short)f2bf(f0) | ((unsigned)(unsigned short)f2bf(f1) << 16);
            *(unsigned*)&Bs[srow][k] = pk;
        }
    }
    __syncthreads();

#pragma unroll
    for (int kk = 0; kk < 128; kk += 32) {
        bf16x8 af = *(const bf16x8*)&As[w * 16 + frow][kk + fk];
#pragma unroll
        for (int ct = 0; ct < 4; ++ct) {
            bf16x8 bfr = *(const bf16x8*)&Bs[ct * 16 + frow][kk + fk];
            acc[ct] = __builtin_amdgcn_mfma_f32_16x16x32_bf16(af, bfr, acc[ct], 0, 0, 0);
        }
    }

    const int rr = r0 + w * 16 + (lane >> 4) * 4;
    const int c0 = n0 + (lane & 15);
#pragma unroll
    for (int ct = 0; ct < 4; ++ct) {
        const int c = c0 + ct * 16;
#pragma unroll
        for (int rg = 0; rg < 4; ++rg) {
            const float v = acc[ct][rg];
            const int r = rr + rg;
            if (c < DI) {
                xs[(size_t)r * DI + c]    = v;
                xs_bf[(size_t)r * DI + c] = f2bf(v);
            } else {
                sz[(size_t)r * DI + (c - DI)] = v / (1.f + __expf(-v));
            }
        }
    }
}

// ---------------------------------------------------------------------------
// kernel 2: dbc GEMM — 192 blocks x 512 thr, tile 64r x 128c, K=256
// ---------------------------------------------------------------------------
__global__ __launch_bounds__(512) void k_dbc(
    const short* __restrict__ xs_bf, const short* __restrict__ WdbcT,
    const float* __restrict__ xs,
    float* __restrict__ dlt, float* __restrict__ u, float* __restrict__ cvv)
{
    __shared__ short As[64][72], Bs[128][72];
    const int blk = blockIdx.x, t = threadIdx.x;
    const int w8 = t >> 6, lane = t & 63;
    const int rf = w8 & 3, ch = w8 >> 2;
    const int frow = lane & 15, fk = (lane >> 4) << 3;
    const int bx = blk % 6, by = blk / 6;
    const int r0 = by * 64, n0 = bx * 128;
    const int arow = t >> 3, ak = (t & 7) * 8;
    const int brow = t >> 2, bk = (t & 3) * 16;
    f32x4 acc[4] = {};

    for (int k0 = 0; k0 < DI; k0 += 64) {
        bf16x8 a0 = *(const bf16x8*)(xs_bf + (size_t)(r0 + arow) * DI + k0 + ak);
        bf16x8 b0 = *(const bf16x8*)(WdbcT + (size_t)(n0 + brow) * DI + k0 + bk);
        bf16x8 b1 = *(const bf16x8*)(WdbcT + (size_t)(n0 + brow) * DI + k0 + bk + 8);
        __syncthreads();
        *(bf16x8*)&As[arow][ak]     = a0;
        *(bf16x8*)&Bs[brow][bk]     = b0;
        *(bf16x8*)&Bs[brow][bk + 8] = b1;
        __syncthreads();
#pragma unroll
        for (int kk = 0; kk < 64; kk += 32) {
            bf16x8 af = *(const bf16x8*)&As[rf * 16 + frow][kk + fk];
#pragma unroll
            for (int ct = 0; ct < 4; ++ct) {
                bf16x8 bfr = *(const bf16x8*)&Bs[(ch * 4 + ct) * 16 + frow][kk + fk];
                acc[ct] = __builtin_amdgcn_mfma_f32_16x16x32_bf16(af, bfr, acc[ct], 0, 0, 0);
            }
        }
    }

    const int rr = r0 + rf * 16 + (lane >> 4) * 4;
    const int nbase = n0 + ch * 64;
    const int wsel = nbase >> 8;          // 0: delta, 1: B, 2: C
    const int nb = nbase & 255;
#pragma unroll
    for (int ct = 0; ct < 4; ++ct) {
        const int c = nb + ct * 16 + (lane & 15);
#pragma unroll
        for (int rg = 0; rg < 4; ++rg) {
            const float v = acc[ct][rg];
            const size_t idx = (size_t)(rr + rg) * DI + c;
            if (wsel == 0)      dlt[idx] = v;
            else if (wsel == 1) u[idx]   = v * xs[idx];   // Bv * xs
            else                cvv[idx] = v;
        }
    }
}

// ---------------------------------------------------------------------------
// kernel 3: scan pass 1 — chunk-local states, 2-deep register dbuf prefetch.
// 448 blocks: chunks 0..6 only (chunk 7's T/dsum are never consumed).
// ---------------------------------------------------------------------------
__global__ __launch_bounds__(256) void k_scan1(
    const float* __restrict__ dlt, const float* __restrict__ u,
    const float* __restrict__ Aa,
    float* __restrict__ tc, float* __restrict__ dsm)
{
    const int lane = threadIdx.x & 63;
    const int w    = threadIdx.x >> 6;
    const int blk  = blockIdx.x;
    const int b  = blk & 3;
    const int r  = blk >> 2;          // 0..111
    const int c  = r % 7;             // 0..6
    const int d0 = ((r / 7) * 4 + w) * 4;

    __shared__ float dls[4][4][LC];
    const size_t base = (size_t)b * LLEN * DI + (size_t)c * LC * DI;

    float4 dv = *(const float4*)(dlt + base + (size_t)lane * DI + d0);
    dls[w][0][lane] = dv.x;
    dls[w][1][lane] = dv.y;
    dls[w][2][lane] = dv.z;
    dls[w][3][lane] = dv.w;
    float dsv[4] = { dv.x, dv.y, dv.z, dv.w };
#pragma unroll
    for (int dd = 0; dd < 4; ++dd) {
#pragma unroll
        for (int off = 32; off > 0; off >>= 1)
            dsv[dd] += __shfl_xor(dsv[dd], off);
    }

    float4 c1[4], c2[4];
#pragma unroll
    for (int dd = 0; dd < 4; ++dd) {
        float4 a = *(const float4*)(Aa + (size_t)(d0 + dd) * DS + lane * 4);
        c1[dd] = a;
        c2[dd] = make_float4(0.5f * a.x * a.x, 0.5f * a.y * a.y,
                             0.5f * a.z * a.z, 0.5f * a.w * a.w);
    }

    const float4* up = (const float4*)(u + base) + lane;
    float4 s[4] = {};
    float4 uA[4], uB[4];

#define S1_PRE(UB, G)                                                         \
    {                                                                         \
        _Pragma("unroll")                                                     \
        for (int i = 0; i < 4; ++i)                                           \
            UB[i] = up[(size_t)((G) * 4 + i) * 64];                           \
    }

#define S1_COMP(UB, G)                                                        \
    {                                                                         \
        _Pragma("unroll")                                                     \
        for (int i = 0; i < 4; ++i) {                                         \
            const int l = (G) * 4 + i;                                        \
            _Pragma("unroll")                                                 \
            for (int dd = 0; dd < 4; ++dd) {                                  \
                const float dl = dls[w][dd][l];                               \
                s[dd].x = fmaf(TEXP2(c1[dd].x, c2[dd].x, dl), s[dd].x, dl * UB[i].x); \
                s[dd].y = fmaf(TEXP2(c1[dd].y, c2[dd].y, dl), s[dd].y, dl * UB[i].y); \
                s[dd].z = fmaf(TEXP2(c1[dd].z, c2[dd].z, dl), s[dd].z, dl * UB[i].z); \
                s[dd].w = fmaf(TEXP2(c1[dd].w, c2[dd].w, dl), s[dd].w, dl * UB[i].w); \
            }                                                                 \
        }                                                                     \
    }

    S1_PRE(uA, 0)
    for (int g2 = 0; g2 < 8; ++g2) {
        S1_PRE(uB, g2 * 2 + 1)
        S1_COMP(uA, g2 * 2)
        if (g2 < 7) S1_PRE(uA, g2 * 2 + 2)
        S1_COMP(uB, g2 * 2 + 1)
    }
#undef S1_PRE
#undef S1_COMP

    const size_t rbb = ((size_t)(b * 256 + d0)) * NC + c;
#pragma unroll
    for (int dd = 0; dd < 4; ++dd) {
        *(float4*)(tc + (rbb + (size_t)dd * NC) * 256 + lane * 4) = s[dd];
        if (lane == 0) dsm[rbb + dd * NC] = dsv[dd];
    }
}

// ---------------------------------------------------------------------------
// kernel 4: scan pass 3 — inline chunk-combine prologue + outputs.
// 2-deep register dbuf prefetch; T stride 17 floats (odd): scalar b32 writes
// and flush reads are both <=2-way bank aliased (free). Flush every 4 steps.
// ---------------------------------------------------------------------------
__global__ __launch_bounds__(256) void k_scan3(
    const float* __restrict__ dlt, const float* __restrict__ u,
    const float* __restrict__ cvv, const float* __restrict__ Aa,
    const float* __restrict__ tc, const float* __restrict__ dsm,
    float* __restrict__ yv)
{
    const int lane = threadIdx.x & 63;
    const int w    = threadIdx.x >> 6;
    const int blk  = blockIdx.x;
    const int b  = blk & 3;
    const int c  = (blk >> 2) & 7;
    const int d0 = ((blk >> 5) * 4 + w) * 4;

    __shared__ float dls[4][4][LC];
    __shared__ float T[4][LC][17];      // odd stride: conflict-free b32 R/W

    const size_t base = (size_t)b * LLEN * DI + (size_t)c * LC * DI;

    float4 dv = *(const float4*)(dlt + base + (size_t)lane * DI + d0);
    dls[w][0][lane] = dv.x;
    dls[w][1][lane] = dv.y;
    dls[w][2][lane] = dv.z;
    dls[w][3][lane] = dv.w;

    float4 c1[4], c2[4];
#pragma unroll
    for (int dd = 0; dd < 4; ++dd) {
        float4 a = *(const float4*)(Aa + (size_t)(d0 + dd) * DS + lane * 4);
        c1[dd] = a;
        c2[dd] = make_float4(0.5f * a.x * a.x, 0.5f * a.y * a.y,
                             0.5f * a.z * a.z, 0.5f * a.w * a.w);
    }

    // ---- inline combine: s = s_init[c] from chunks 0..c-1 ----
    float4 s[4] = {};
    for (int cc = 0; cc < c; ++cc) {
#pragma unroll
        for (int dd = 0; dd < 4; ++dd) {
            const size_t rbd = ((size_t)(b * 256 + d0 + dd)) * NC + cc;
            const float4 Tt = *(const float4*)(tc + rbd * 256 + lane * 4);
            const float  Dc = dsm[rbd] * LOG2E;
            s[dd].x = exp2f(c1[dd].x * Dc) * s[dd].x + Tt.x;
            s[dd].y = exp2f(c1[dd].y * Dc) * s[dd].y + Tt.y;
            s[dd].z = exp2f(c1[dd].z * Dc) * s[dd].z + Tt.z;
            s[dd].w = exp2f(c1[dd].w * Dc) * s[dd].w + Tt.w;
        }
    }

    const float4* up = (const float4*)(u + base) + lane;
    const float4* cp = (const float4*)(cvv + base) + lane;
    float* yb = yv + base;

    const int col = lane & 15, seg = lane >> 4;
    float4 uA[4], cA[4], uB[4], cB[4];

#define S3_PRE(UB, CB, G)                                                     \
    {                                                                         \
        _Pragma("unroll")                                                     \
        for (int i = 0; i < 4; ++i) {                                         \
            UB[i] = up[(size_t)((G) * 4 + i) * 64];                           \
            CB[i] = cp[(size_t)((G) * 4 + i) * 64];                           \
        }                                                                     \
    }

#define S3_COMP(UB, CB, G)                                                    \
    {                                                                         \
        _Pragma("unroll")                                                     \
        for (int i = 0; i < 4; ++i) {                                         \
            const int l = (G) * 4 + i;                                        \
            _Pragma("unroll")                                                 \
            for (int dd = 0; dd < 4; ++dd) {                                  \
                const float dl = dls[w][dd][l];                               \
                s[dd].x = fmaf(TEXP2(c1[dd].x, c2[dd].x, dl), s[dd].x, dl * UB[i].x); \
                s[dd].y = fmaf(TEXP2(c1[dd].y, c2[dd].y, dl), s[dd].y, dl * UB[i].y); \
                s[dd].z = fmaf(TEXP2(c1[dd].z, c2[dd].z, dl), s[dd].z, dl * UB[i].z); \
                s[dd].w = fmaf(TEXP2(c1[dd].w, c2[dd].w, dl), s[dd].w, dl * UB[i].w); \
                T[w][lane][dd * 4 + i] =                                      \
                    fmaf(s[dd].w, CB[i].w, fmaf(s[dd].z, CB[i].z,             \
                         fmaf(s[dd].y, CB[i].y, s[dd].x * CB[i].x)));         \
            }                                                                 \
        }                                                                     \
        float sm = 0.f;                                                       \
        _Pragma("unroll")                                                     \
        for (int r = 0; r < 16; ++r)                                          \
            sm += T[w][seg * 16 + r][col];                                    \
        sm += __shfl_xor(sm, 16);                                             \
        sm += __shfl_xor(sm, 32);                                             \
        if (lane < 16)                                                        \
            yb[(size_t)((G) * 4 + (col & 3)) * DI + d0 + (col >> 2)] = sm;    \
    }

    S3_PRE(uA, cA, 0)
    for (int g2 = 0; g2 < 8; ++g2) {
        S3_PRE(uB, cB, g2 * 2 + 1)
        S3_COMP(uA, cA, g2 * 2)
        if (g2 < 7) S3_PRE(uA, cA, g2 * 2 + 2)
        S3_COMP(uB, cB, g2 * 2 + 1)
    }
#undef S3_PRE
#undef S3_COMP
}

// ---------------------------------------------------------------------------
// kernel 5: out GEMM (MFMA) — 64 blocks x 256 thr
// ---------------------------------------------------------------------------
__global__ __launch_bounds__(256) void k_out_mfma(
    const float* __restrict__ y, const float* __restrict__ szp,
    const short* __restrict__ W_outT, float* __restrict__ out)
{
    __shared__ short As[64][72], Bs[64][72];
    f32x4 acc[4] = {};
    const int tid  = threadIdx.x;
    const int w    = tid >> 6, lane = tid & 63;
    const int srow = tid >> 2, sseg = tid & 3;
    const int frow = lane & 15, fk = (lane >> 4) << 3;
    const int r0 = blockIdx.y * 64, n0 = blockIdx.x * 64;

    for (int k0 = 0; k0 < DI; k0 += 64) {
        const size_t aoff = (size_t)(r0 + srow) * DI + k0 + sseg * 16;
        float4 y0 = *(const float4*)(y + aoff);
        float4 y1 = *(const float4*)(y + aoff + 4);
        float4 y2 = *(const float4*)(y + aoff + 8);
        float4 y3 = *(const float4*)(y + aoff + 12);
        float4 s0 = *(const float4*)(szp + aoff);
        float4 s1 = *(const float4*)(szp + aoff + 4);
        float4 s2 = *(const float4*)(szp + aoff + 8);
        float4 s3 = *(const float4*)(szp + aoff + 12);
        const short* bg = W_outT + (size_t)(n0 + srow) * DI + k0 + sseg * 16;
        bf16x8 b0 = *(const bf16x8*)bg;
        bf16x8 b1 = *(const bf16x8*)(bg + 8);
        bf16x8 a0, a1;
        a0[0] = f2bf(y0.x * s0.x); a0[1] = f2bf(y0.y * s0.y);
        a0[2] = f2bf(y0.z * s0.z); a0[3] = f2bf(y0.w * s0.w);
        a0[4] = f2bf(y1.x * s1.x); a0[5] = f2bf(y1.y * s1.y);
        a0[6] = f2bf(y1.z * s1.z); a0[7] = f2bf(y1.w * s1.w);
        a1[0] = f2bf(y2.x * s2.x); a1[1] = f2bf(y2.y * s2.y);
        a1[2] = f2bf(y2.z * s2.z); a1[3] = f2bf(y2.w * s2.w);
        a1[4] = f2bf(y3.x * s3.x); a1[5] = f2bf(y3.y * s3.y);
        a1[6] = f2bf(y3.z * s3.z); a1[7] = f2bf(y3.w * s3.w);
        __syncthreads();
        *(bf16x8*)&As[srow][sseg * 16]     = a0;
        *(bf16x8*)&As[srow][sseg * 16 + 8] = a1;
        *(bf16x8*)&Bs[srow][sseg * 16]     = b0;
        *(bf16x8*)&Bs[srow][sseg * 16 + 8] = b1;
        __syncthreads();
#pragma unroll
        for (int kk = 0; kk < 64; kk += 32) {
            bf16x8 af = *(const bf16x8*)&As[w * 16 + frow][kk + fk];
#pragma unroll
            for (int ct = 0; ct < 4; ++ct) {
                bf16x8 bfr = *(const bf16x8*)&Bs[ct * 16 + frow][kk + fk];
                acc[ct] = __builtin_amdgcn_mfma_f32_16x16x32_bf16(af, bfr, acc[ct], 0, 0, 0);
            }
        }
    }

    const int rr = r0 + w * 16 + (lane >> 4) * 4;
    const int c0 = n0 + (lane & 15);
#pragma unroll
    for (int ct = 0; ct < 4; ++ct) {
        const int c = c0 + ct * 16;
#pragma unroll
        for (int rg = 0; rg < 4; ++rg)
            out[(size_t)(rr + rg) * DM + c] = acc[ct][rg];
    }
}

// ---------------------------------------------------------------------------
extern "C" void kernel_launch(void* const* d_in, const int* in_sizes, int n_in,
                              void* d_out, int out_size, void* d_ws, size_t ws_size,
                              hipStream_t stream)
{
    const float* x       = (const float*)d_in[0];
    const float* W_in    = (const float*)d_in[1];
    const float* W_delta = (const float*)d_in[2];
    const float* W_B     = (const float*)d_in[3];
    const float* W_C     = (const float*)d_in[4];
    const float* W_out   = (const float*)d_in[5];
    const float* A       = (const float*)d_in[6];
    // d_in[7] = D, unused by the reference scan

    float* out = (float*)d_out;
    float* ws  = (float*)d_ws;

    const size_t S = (size_t)MROWS * DI;   // 524288 floats per plane (2 MB)
    float* xs  = ws;
    float* sz  = ws + S;
    float* dlt = ws + 2 * S;
    float* u   = ws + 3 * S;
    float* cv  = ws + 4 * S;
    float* yv  = ws + 5 * S;
    float* tc  = ws + 6 * S;                              // 1024*8*256 = 8 MB
    float* dsm = tc + (size_t)1024 * NC * 256;            // 8192 floats

    short* xs_bf  = (short*)(dsm + (size_t)1024 * NC);    // 2048*256
    short* WdbcT  = xs_bf + (size_t)MROWS * DI;           // 768*256
    short* W_outT = WdbcT + (size_t)768 * DI;             // 128*256

    k_proj_mfma<<<dim3(15, 32), 256, 0, stream>>>(x, W_in, W_delta, W_B, W_C, W_out,
                                                  xs, xs_bf, sz, WdbcT, W_outT);
    k_dbc      <<<dim3(192), 512, 0, stream>>>(xs_bf, WdbcT, xs, dlt, u, cv);
    k_scan1    <<<dim3(448), 256, 0, stream>>>(dlt, u, A, tc, dsm);
    k_scan3    <<<dim3(512), 256, 0, stream>>>(dlt, u, cv, A, tc, dsm, yv);
    k_out_mfma <<<dim3(2, 32), 256, 0, stream>>>(yv, sz, W_outT, out);
}

// Round 16
// 68.978 us; speedup vs baseline: 1.7575x; 1.0044x over previous
//
#include <hip/hip_runtime.h>
#include <hip/hip_bf16.h>

// Mamba block: B=4, L=512, D_MODEL=128, D_INNER=D_STATE=256
// 5 launches: [proj MFMA + weight-prep] -> dbc MFMA (64x128 tiles) ->
// scan1 (chunk-local, chunks 0..6, packed-f32 dbuf) ->
// scan3 (inline combine + outputs, packed-f32 dbuf, conflict-free T) -> out MFMA

#define MROWS 2048
#define DM 128
#define DI 256
#define DS 256
#define LLEN 512
#define LC 64
#define NC 8

#define LOG2E 1.44269504088896340736f

typedef short bf16x8 __attribute__((ext_vector_type(8)));
typedef float f32x4  __attribute__((ext_vector_type(4)));
typedef float f32x2  __attribute__((ext_vector_type(2)));

#define FMA2(a, b, c) __builtin_elementwise_fma((a), (b), (c))

__device__ __forceinline__ short f2bf(float f) {
    union { float f; unsigned u; } v; v.f = f;
    unsigned r = v.u + 0x7FFFu + ((v.u >> 16) & 1u);   // RNE
    return (short)(r >> 16);
}

// ---------------------------------------------------------------------------
// 32x32 transpose+convert tile (fp32 src -> bf16 dst, dst N-major)
// ---------------------------------------------------------------------------
__device__ __forceinline__ void tconv(float (*tile)[33],
                                      const float* __restrict__ src,
                                      short* __restrict__ dst,
                                      int Ms, int Ns, int ti, int tj, int tid)
{
    const int r = tid >> 5, c = tid & 31;
#pragma unroll
    for (int i = 0; i < 4; ++i)
        tile[r + 8 * i][c] = src[(size_t)(ti * 32 + r + 8 * i) * Ns + tj * 32 + c];
    __syncthreads();
#pragma unroll
    for (int i = 0; i < 4; ++i)
        dst[(size_t)(tj * 32 + r + 8 * i) * Ms + ti * 32 + c] = f2bf(tile[c][r + 8 * i]);
}

// ---------------------------------------------------------------------------
// kernel 1: in_proj (MFMA) + fused weight-prep blocks  (grid 15x32, 256 thr)
// ---------------------------------------------------------------------------
__global__ __launch_bounds__(256) void k_proj_mfma(
    const float* __restrict__ x, const float* __restrict__ W_in,
    const float* __restrict__ Wd, const float* __restrict__ Wb,
    const float* __restrict__ Wc, const float* __restrict__ W_out,
    float* __restrict__ xs, short* __restrict__ xs_bf, float* __restrict__ sz,
    short* __restrict__ WdbcT, short* __restrict__ W_outT)
{
    const int t = threadIdx.x;

    if (blockIdx.x >= 8) {               // ---- prep role: 224 tiles ----
        __shared__ float tile[32][33];
        const int uu = (blockIdx.x - 8) * 32 + blockIdx.y;
        if (uu < 64)       tconv(tile, Wd,    WdbcT,                       256, 256, uu & 7,         uu >> 3,         t);
        else if (uu < 128) tconv(tile, Wb,    WdbcT + (size_t)256 * 256,   256, 256, (uu - 64) & 7,  (uu - 64) >> 3,  t);
        else if (uu < 192) tconv(tile, Wc,    WdbcT + (size_t)512 * 256,   256, 256, (uu - 128) & 7, (uu - 128) >> 3, t);
        else if (uu < 224) tconv(tile, W_out, W_outT,                      256, 128, (uu - 192) & 7, (uu - 192) >> 3, t);
        return;
    }

    // ---- GEMM role ----
    __shared__ short As[64][136];
    __shared__ short Bs[64][136];
    f32x4 acc[4] = {};
    const int w = t >> 6, lane = t & 63;
    const int srow = t >> 2, sseg = t & 3;
    const int frow = lane & 15, fk = (lane >> 4) << 3;
    const int r0 = blockIdx.y * 64, n0 = blockIdx.x * 64;

    {
        const float* ap = x + (size_t)(r0 + srow) * DM + sseg * 32;
        short tmp[32];
#pragma unroll
        for (int j = 0; j < 8; ++j) {
            float4 f = *(const float4*)(ap + j * 4);
            tmp[j * 4 + 0] = f2bf(f.x); tmp[j * 4 + 1] = f2bf(f.y);
            tmp[j * 4 + 2] = f2bf(f.z); tmp[j * 4 + 3] = f2bf(f.w);
        }
#pragma unroll
        for (int m = 0; m < 4; ++m)
            *(bf16x8*)&As[srow][sseg * 32 + m * 8] = *(bf16x8*)&tmp[m * 8];
    }
    {
#pragma unroll
        for (int i = 0; i < 32; i += 2) {
            const int k = sseg * 32 + i;
            float f0 = W_in[(size_t)k * 512 + n0 + srow];
            float f1 = W_in[(size_t)(k + 1) * 512 + n0 + srow];
            unsigned pk = (unsigned short)f2bf(f0) | ((unsigned)(unsigned short)f2bf(f1) << 16);
            *(unsigned*)&Bs[srow][k] = pk;
        }
    }
    __syncthreads();

#pragma unroll
    for (int kk = 0; kk < 128; kk += 32) {
        bf16x8 af = *(const bf16x8*)&As[w * 16 + frow][kk + fk];
#pragma unroll
        for (int ct = 0; ct < 4; ++ct) {
            bf16x8 bfr = *(const bf16x8*)&Bs[ct * 16 + frow][kk + fk];
            acc[ct] = __builtin_amdgcn_mfma_f32_16x16x32_bf16(af, bfr, acc[ct], 0, 0, 0);
        }
    }

    const int rr = r0 + w * 16 + (lane >> 4) * 4;
    const int c0 = n0 + (lane & 15);
#pragma unroll
    for (int ct = 0; ct < 4; ++ct) {
        const int c = c0 + ct * 16;
#pragma unroll
        for (int rg = 0; rg < 4; ++rg) {
            const float v = acc[ct][rg];
            const int r = rr + rg;
            if (c < DI) {
                xs[(size_t)r * DI + c]    = v;
                xs_bf[(size_t)r * DI + c] = f2bf(v);
            } else {
                sz[(size_t)r * DI + (c - DI)] = v / (1.f + __expf(-v));
            }
        }
    }
}

// ---------------------------------------------------------------------------
// kernel 2: dbc GEMM — 192 blocks x 512 thr, tile 64r x 128c, K=256
// ---------------------------------------------------------------------------
__global__ __launch_bounds__(512) void k_dbc(
    const short* __restrict__ xs_bf, const short* __restrict__ WdbcT,
    const float* __restrict__ xs,
    float* __restrict__ dlt, float* __restrict__ u, float* __restrict__ cvv)
{
    __shared__ short As[64][72], Bs[128][72];
    const int blk = blockIdx.x, t = threadIdx.x;
    const int w8 = t >> 6, lane = t & 63;
    const int rf = w8 & 3, ch = w8 >> 2;
    const int frow = lane & 15, fk = (lane >> 4) << 3;
    const int bx = blk % 6, by = blk / 6;
    const int r0 = by * 64, n0 = bx * 128;
    const int arow = t >> 3, ak = (t & 7) * 8;
    const int brow = t >> 2, bk = (t & 3) * 16;
    f32x4 acc[4] = {};

    for (int k0 = 0; k0 < DI; k0 += 64) {
        bf16x8 a0 = *(const bf16x8*)(xs_bf + (size_t)(r0 + arow) * DI + k0 + ak);
        bf16x8 b0 = *(const bf16x8*)(WdbcT + (size_t)(n0 + brow) * DI + k0 + bk);
        bf16x8 b1 = *(const bf16x8*)(WdbcT + (size_t)(n0 + brow) * DI + k0 + bk + 8);
        __syncthreads();
        *(bf16x8*)&As[arow][ak]     = a0;
        *(bf16x8*)&Bs[brow][bk]     = b0;
        *(bf16x8*)&Bs[brow][bk + 8] = b1;
        __syncthreads();
#pragma unroll
        for (int kk = 0; kk < 64; kk += 32) {
            bf16x8 af = *(const bf16x8*)&As[rf * 16 + frow][kk + fk];
#pragma unroll
            for (int ct = 0; ct < 4; ++ct) {
                bf16x8 bfr = *(const bf16x8*)&Bs[(ch * 4 + ct) * 16 + frow][kk + fk];
                acc[ct] = __builtin_amdgcn_mfma_f32_16x16x32_bf16(af, bfr, acc[ct], 0, 0, 0);
            }
        }
    }

    const int rr = r0 + rf * 16 + (lane >> 4) * 4;
    const int nbase = n0 + ch * 64;
    const int wsel = nbase >> 8;          // 0: delta, 1: B, 2: C
    const int nb = nbase & 255;
#pragma unroll
    for (int ct = 0; ct < 4; ++ct) {
        const int c = nb + ct * 16 + (lane & 15);
#pragma unroll
        for (int rg = 0; rg < 4; ++rg) {
            const float v = acc[ct][rg];
            const size_t idx = (size_t)(rr + rg) * DI + c;
            if (wsel == 0)      dlt[idx] = v;
            else if (wsel == 1) u[idx]   = v * xs[idx];   // Bv * xs
            else                cvv[idx] = v;
        }
    }
}

// ---------------------------------------------------------------------------
// kernel 3: scan pass 1 — chunk-local states, packed-f32, dbuf prefetch.
// 448 blocks: chunks 0..6 only. Delta in LDS as float4 per step (1x b128).
// ---------------------------------------------------------------------------
__global__ __launch_bounds__(256) void k_scan1(
    const float* __restrict__ dlt, const float* __restrict__ u,
    const float* __restrict__ Aa,
    float* __restrict__ tc, float* __restrict__ dsm)
{
    const int lane = threadIdx.x & 63;
    const int w    = threadIdx.x >> 6;
    const int blk  = blockIdx.x;
    const int b  = blk & 3;
    const int r  = blk >> 2;          // 0..111
    const int c  = r % 7;             // 0..6
    const int d0 = ((r / 7) * 4 + w) * 4;

    __shared__ float4 dls4[4][LC];
    const size_t base = (size_t)b * LLEN * DI + (size_t)c * LC * DI;

    float4 dv = *(const float4*)(dlt + base + (size_t)lane * DI + d0);
    dls4[w][lane] = dv;
    float dsv[4] = { dv.x, dv.y, dv.z, dv.w };
#pragma unroll
    for (int dd = 0; dd < 4; ++dd) {
#pragma unroll
        for (int off = 32; off > 0; off >>= 1)
            dsv[dd] += __shfl_xor(dsv[dd], off);
    }

    const f32x2 one2 = {1.f, 1.f};
    f32x2 c1a[4], c1b[4], c2a[4], c2b[4];
#pragma unroll
    for (int dd = 0; dd < 4; ++dd) {
        float4 a = *(const float4*)(Aa + (size_t)(d0 + dd) * DS + lane * 4);
        c1a[dd] = (f32x2){a.x, a.y};
        c1b[dd] = (f32x2){a.z, a.w};
        c2a[dd] = (f32x2){0.5f * a.x * a.x, 0.5f * a.y * a.y};
        c2b[dd] = (f32x2){0.5f * a.z * a.z, 0.5f * a.w * a.w};
    }

    const float4* up = (const float4*)(u + base) + lane;
    f32x2 s0[4] = {}, s1[4] = {};
    float4 uA[4], uB[4];

#define S1_PRE(UB, G)                                                         \
    {                                                                         \
        _Pragma("unroll")                                                     \
        for (int i = 0; i < 4; ++i)                                           \
            UB[i] = up[(size_t)((G) * 4 + i) * 64];                           \
    }

#define S1_COMP(UB, G)                                                        \
    {                                                                         \
        _Pragma("unroll")                                                     \
        for (int i = 0; i < 4; ++i) {                                         \
            const float4 d4 = dls4[w][(G) * 4 + i];                           \
            const float dla[4] = { d4.x, d4.y, d4.z, d4.w };                  \
            const f32x2 u01 = (f32x2){UB[i].x, UB[i].y};                      \
            const f32x2 u23 = (f32x2){UB[i].z, UB[i].w};                      \
            _Pragma("unroll")                                                 \
            for (int dd = 0; dd < 4; ++dd) {                                  \
                const f32x2 dl2 = (f32x2){dla[dd], dla[dd]};                  \
                f32x2 e0 = FMA2(c2a[dd], dl2, c1a[dd]); e0 = FMA2(e0, dl2, one2); \
                f32x2 e1 = FMA2(c2b[dd], dl2, c1b[dd]); e1 = FMA2(e1, dl2, one2); \
                s0[dd] = FMA2(e0, s0[dd], dl2 * u01);                         \
                s1[dd] = FMA2(e1, s1[dd], dl2 * u23);                         \
            }                                                                 \
        }                                                                     \
    }

    S1_PRE(uA, 0)
    for (int g2 = 0; g2 < 8; ++g2) {
        S1_PRE(uB, g2 * 2 + 1)
        S1_COMP(uA, g2 * 2)
        if (g2 < 7) S1_PRE(uA, g2 * 2 + 2)
        S1_COMP(uB, g2 * 2 + 1)
    }
#undef S1_PRE
#undef S1_COMP

    const size_t rbb = ((size_t)(b * 256 + d0)) * NC + c;
#pragma unroll
    for (int dd = 0; dd < 4; ++dd) {
        *(float4*)(tc + (rbb + (size_t)dd * NC) * 256 + lane * 4) =
            make_float4(s0[dd][0], s0[dd][1], s1[dd][0], s1[dd][1]);
        if (lane == 0) dsm[rbb + dd * NC] = dsv[dd];
    }
}

// ---------------------------------------------------------------------------
// kernel 4: scan pass 3 — inline chunk-combine prologue + outputs.
// Packed-f32 state update; dbuf prefetch; T stride 17 (conflict-free);
// flush every 4 steps.
// ---------------------------------------------------------------------------
__global__ __launch_bounds__(256) void k_scan3(
    const float* __restrict__ dlt, const float* __restrict__ u,
    const float* __restrict__ cvv, const float* __restrict__ Aa,
    const float* __restrict__ tc, const float* __restrict__ dsm,
    float* __restrict__ yv)
{
    const int lane = threadIdx.x & 63;
    const int w    = threadIdx.x >> 6;
    const int blk  = blockIdx.x;
    const int b  = blk & 3;
    const int c  = (blk >> 2) & 7;
    const int d0 = ((blk >> 5) * 4 + w) * 4;

    __shared__ float4 dls4[4][LC];
    __shared__ float T[4][LC][17];      // odd stride: conflict-free b32 R/W

    const size_t base = (size_t)b * LLEN * DI + (size_t)c * LC * DI;

    float4 dv = *(const float4*)(dlt + base + (size_t)lane * DI + d0);
    dls4[w][lane] = dv;

    const f32x2 one2 = {1.f, 1.f};
    f32x2 c1a[4], c1b[4], c2a[4], c2b[4];
#pragma unroll
    for (int dd = 0; dd < 4; ++dd) {
        float4 a = *(const float4*)(Aa + (size_t)(d0 + dd) * DS + lane * 4);
        c1a[dd] = (f32x2){a.x, a.y};
        c1b[dd] = (f32x2){a.z, a.w};
        c2a[dd] = (f32x2){0.5f * a.x * a.x, 0.5f * a.y * a.y};
        c2b[dd] = (f32x2){0.5f * a.z * a.z, 0.5f * a.w * a.w};
    }

    // ---- inline combine: s = s_init[c] from chunks 0..c-1 ----
    f32x2 s0[4] = {}, s1[4] = {};
    for (int cc = 0; cc < c; ++cc) {
#pragma unroll
        for (int dd = 0; dd < 4; ++dd) {
            const size_t rbd = ((size_t)(b * 256 + d0 + dd)) * NC + cc;
            const float4 Tt = *(const float4*)(tc + rbd * 256 + lane * 4);
            const float  Dc = dsm[rbd] * LOG2E;
            s0[dd][0] = exp2f(c1a[dd][0] * Dc) * s0[dd][0] + Tt.x;
            s0[dd][1] = exp2f(c1a[dd][1] * Dc) * s0[dd][1] + Tt.y;
            s1[dd][0] = exp2f(c1b[dd][0] * Dc) * s1[dd][0] + Tt.z;
            s1[dd][1] = exp2f(c1b[dd][1] * Dc) * s1[dd][1] + Tt.w;
        }
    }

    const float4* up = (const float4*)(u + base) + lane;
    const float4* cp = (const float4*)(cvv + base) + lane;
    float* yb = yv + base;

    const int col = lane & 15, seg = lane >> 4;
    float4 uA[4], cA[4], uB[4], cB[4];

#define S3_PRE(UB, CB, G)                                                     \
    {                                                                         \
        _Pragma("unroll")                                                     \
        for (int i = 0; i < 4; ++i) {                                         \
            UB[i] = up[(size_t)((G) * 4 + i) * 64];                           \
            CB[i] = cp[(size_t)((G) * 4 + i) * 64];                           \
        }                                                                     \
    }

#define S3_COMP(UB, CB, G)                                                    \
    {                                                                         \
        _Pragma("unroll")                                                     \
        for (int i = 0; i < 4; ++i) {                                         \
            const float4 d4 = dls4[w][(G) * 4 + i];                           \
            const float dla[4] = { d4.x, d4.y, d4.z, d4.w };                  \
            const f32x2 u01 = (f32x2){UB[i].x, UB[i].y};                      \
            const f32x2 u23 = (f32x2){UB[i].z, UB[i].w};                      \
            const f32x2 c01 = (f32x2){CB[i].x, CB[i].y};                      \
            const f32x2 c23 = (f32x2){CB[i].z, CB[i].w};                      \
            _Pragma("unroll")                                                 \
            for (int dd = 0; dd < 4; ++dd) {                                  \
                const f32x2 dl2 = (f32x2){dla[dd], dla[dd]};                  \
                f32x2 e0 = FMA2(c2a[dd], dl2, c1a[dd]); e0 = FMA2(e0, dl2, one2); \
                f32x2 e1 = FMA2(c2b[dd], dl2, c1b[dd]); e1 = FMA2(e1, dl2, one2); \
                s0[dd] = FMA2(e0, s0[dd], dl2 * u01);                         \
                s1[dd] = FMA2(e1, s1[dd], dl2 * u23);                         \
                f32x2 q = s0[dd] * c01;                                       \
                q = FMA2(s1[dd], c23, q);                                     \
                T[w][lane][dd * 4 + i] = q[0] + q[1];                         \
            }                                                                 \
        }                                                                     \
        float sm = 0.f;                                                       \
        _Pragma("unroll")                                                     \
        for (int rr2 = 0; rr2 < 16; ++rr2)                                    \
            sm += T[w][seg * 16 + rr2][col];                                  \
        sm += __shfl_xor(sm, 16);                                             \
        sm += __shfl_xor(sm, 32);                                             \
        if (lane < 16)                                                        \
            yb[(size_t)((G) * 4 + (col & 3)) * DI + d0 + (col >> 2)] = sm;    \
    }

    S3_PRE(uA, cA, 0)
    for (int g2 = 0; g2 < 8; ++g2) {
        S3_PRE(uB, cB, g2 * 2 + 1)
        S3_COMP(uA, cA, g2 * 2)
        if (g2 < 7) S3_PRE(uA, cA, g2 * 2 + 2)
        S3_COMP(uB, cB, g2 * 2 + 1)
    }
#undef S3_PRE
#undef S3_COMP
}

// ---------------------------------------------------------------------------
// kernel 5: out GEMM (MFMA) — 64 blocks x 256 thr
// ---------------------------------------------------------------------------
__global__ __launch_bounds__(256) void k_out_mfma(
    const float* __restrict__ y, const float* __restrict__ szp,
    const short* __restrict__ W_outT, float* __restrict__ out)
{
    __shared__ short As[64][72], Bs[64][72];
    f32x4 acc[4] = {};
    const int tid  = threadIdx.x;
    const int w    = tid >> 6, lane = tid & 63;
    const int srow = tid >> 2, sseg = tid & 3;
    const int frow = lane & 15, fk = (lane >> 4) << 3;
    const int r0 = blockIdx.y * 64, n0 = blockIdx.x * 64;

    for (int k0 = 0; k0 < DI; k0 += 64) {
        const size_t aoff = (size_t)(r0 + srow) * DI + k0 + sseg * 16;
        float4 y0 = *(const float4*)(y + aoff);
        float4 y1 = *(const float4*)(y + aoff + 4);
        float4 y2 = *(const float4*)(y + aoff + 8);
        float4 y3 = *(const float4*)(y + aoff + 12);
        float4 s0 = *(const float4*)(szp + aoff);
        float4 s1 = *(const float4*)(szp + aoff + 4);
        float4 s2 = *(const float4*)(szp + aoff + 8);
        float4 s3 = *(const float4*)(szp + aoff + 12);
        const short* bg = W_outT + (size_t)(n0 + srow) * DI + k0 + sseg * 16;
        bf16x8 b0 = *(const bf16x8*)bg;
        bf16x8 b1 = *(const bf16x8*)(bg + 8);
        bf16x8 a0, a1;
        a0[0] = f2bf(y0.x * s0.x); a0[1] = f2bf(y0.y * s0.y);
        a0[2] = f2bf(y0.z * s0.z); a0[3] = f2bf(y0.w * s0.w);
        a0[4] = f2bf(y1.x * s1.x); a0[5] = f2bf(y1.y * s1.y);
        a0[6] = f2bf(y1.z * s1.z); a0[7] = f2bf(y1.w * s1.w);
        a1[0] = f2bf(y2.x * s2.x); a1[1] = f2bf(y2.y * s2.y);
        a1[2] = f2bf(y2.z * s2.z); a1[3] = f2bf(y2.w * s2.w);
        a1[4] = f2bf(y3.x * s3.x); a1[5] = f2bf(y3.y * s3.y);
        a1[6] = f2bf(y3.z * s3.z); a1[7] = f2bf(y3.w * s3.w);
        __syncthreads();
        *(bf16x8*)&As[srow][sseg * 16]     = a0;
        *(bf16x8*)&As[srow][sseg * 16 + 8] = a1;
        *(bf16x8*)&Bs[srow][sseg * 16]     = b0;
        *(bf16x8*)&Bs[srow][sseg * 16 + 8] = b1;
        __syncthreads();
#pragma unroll
        for (int kk = 0; kk < 64; kk += 32) {
            bf16x8 af = *(const bf16x8*)&As[w * 16 + frow][kk + fk];
#pragma unroll
            for (int ct = 0; ct < 4; ++ct) {
                bf16x8 bfr = *(const bf16x8*)&Bs[ct * 16 + frow][kk + fk];
                acc[ct] = __builtin_amdgcn_mfma_f32_16x16x32_bf16(af, bfr, acc[ct], 0, 0, 0);
            }
        }
    }

    const int rr = r0 + w * 16 + (lane >> 4) * 4;
    const int c0 = n0 + (lane & 15);
#pragma unroll
    for (int ct = 0; ct < 4; ++ct) {
        const int c = c0 + ct * 16;
#pragma unroll
        for (int rg = 0; rg < 4; ++rg)
            out[(size_t)(rr + rg) * DM + c] = acc[ct][rg];
    }
}

// ---------------------------------------------------------------------------
extern "C" void kernel_launch(void* const* d_in, const int* in_sizes, int n_in,
                              void* d_out, int out_size, void* d_ws, size_t ws_size,
                              hipStream_t stream)
{
    const float* x       = (const float*)d_in[0];
    const float* W_in    = (const float*)d_in[1];
    const float* W_delta = (const float*)d_in[2];
    const float* W_B     = (const float*)d_in[3];
    const float* W_C     = (const float*)d_in[4];
    const float* W_out   = (const float*)d_in[5];
    const float* A       = (const float*)d_in[6];
    // d_in[7] = D, unused by the reference scan

    float* out = (float*)d_out;
    float* ws  = (float*)d_ws;

    const size_t S = (size_t)MROWS * DI;   // 524288 floats per plane (2 MB)
    float* xs  = ws;
    float* sz  = ws + S;
    float* dlt = ws + 2 * S;
    float* u   = ws + 3 * S;
    float* cv  = ws + 4 * S;
    float* yv  = ws + 5 * S;
    float* tc  = ws + 6 * S;                              // 1024*8*256 = 8 MB
    float* dsm = tc + (size_t)1024 * NC * 256;            // 8192 floats

    short* xs_bf  = (short*)(dsm + (size_t)1024 * NC);    // 2048*256
    short* WdbcT  = xs_bf + (size_t)MROWS * DI;           // 768*256
    short* W_outT = WdbcT + (size_t)768 * DI;             // 128*256

    k_proj_mfma<<<dim3(15, 32), 256, 0, stream>>>(x, W_in, W_delta, W_B, W_C, W_out,
                                                  xs, xs_bf, sz, WdbcT, W_outT);
    k_dbc      <<<dim3(192), 512, 0, stream>>>(xs_bf, WdbcT, xs, dlt, u, cv);
    k_scan1    <<<dim3(448), 256, 0, stream>>>(dlt, u, A, tc, dsm);
    k_scan3    <<<dim3(512), 256, 0, stream>>>(dlt, u, cv, A, tc, dsm, yv);
    k_out_mfma <<<dim3(2, 32), 256, 0, stream>>>(yv, sz, W_outT, out);
}

// Round 17
// 65.839 us; speedup vs baseline: 1.8412x; 1.0477x over previous
//
#include <hip/hip_runtime.h>
#include <hip/hip_bf16.h>

// Mamba block: B=4, L=512, D_MODEL=128, D_INNER=D_STATE=256
// 5 launches with consistent XCD affinity (blk%8 -> XCD; key f(b,c)=((c&1)<<2)|b):
// [proj MFMA + weight-prep] -> dbc MFMA -> scan1 -> scan3 -> out MFMA

#define MROWS 2048
#define DM 128
#define DI 256
#define DS 256
#define LLEN 512
#define LC 64
#define NC 8

#define LOG2E 1.44269504088896340736f

typedef short bf16x8 __attribute__((ext_vector_type(8)));
typedef float f32x4  __attribute__((ext_vector_type(4)));
typedef float f32x2  __attribute__((ext_vector_type(2)));

#define FMA2(a, b, c) __builtin_elementwise_fma((a), (b), (c))

__device__ __forceinline__ short f2bf(float f) {
    union { float f; unsigned u; } v; v.f = f;
    unsigned r = v.u + 0x7FFFu + ((v.u >> 16) & 1u);   // RNE
    return (short)(r >> 16);
}

// ---------------------------------------------------------------------------
// 32x32 transpose+convert tile (fp32 src -> bf16 dst, dst N-major)
// ---------------------------------------------------------------------------
__device__ __forceinline__ void tconv(float (*tile)[33],
                                      const float* __restrict__ src,
                                      short* __restrict__ dst,
                                      int Ms, int Ns, int ti, int tj, int tid)
{
    const int r = tid >> 5, c = tid & 31;
#pragma unroll
    for (int i = 0; i < 4; ++i)
        tile[r + 8 * i][c] = src[(size_t)(ti * 32 + r + 8 * i) * Ns + tj * 32 + c];
    __syncthreads();
#pragma unroll
    for (int i = 0; i < 4; ++i)
        dst[(size_t)(tj * 32 + r + 8 * i) * Ms + ti * 32 + c] = f2bf(tile[c][r + 8 * i]);
}

// ---------------------------------------------------------------------------
// kernel 1: in_proj (MFMA) + fused weight-prep blocks  (grid 15x32, 256 thr)
// ---------------------------------------------------------------------------
__global__ __launch_bounds__(256) void k_proj_mfma(
    const float* __restrict__ x, const float* __restrict__ W_in,
    const float* __restrict__ Wd, const float* __restrict__ Wb,
    const float* __restrict__ Wc, const float* __restrict__ W_out,
    float* __restrict__ xs, short* __restrict__ xs_bf, float* __restrict__ sz,
    short* __restrict__ WdbcT, short* __restrict__ W_outT)
{
    const int t = threadIdx.x;

    if (blockIdx.x >= 8) {               // ---- prep role: 224 tiles ----
        __shared__ float tile[32][33];
        const int uu = (blockIdx.x - 8) * 32 + blockIdx.y;
        if (uu < 64)       tconv(tile, Wd,    WdbcT,                       256, 256, uu & 7,         uu >> 3,         t);
        else if (uu < 128) tconv(tile, Wb,    WdbcT + (size_t)256 * 256,   256, 256, (uu - 64) & 7,  (uu - 64) >> 3,  t);
        else if (uu < 192) tconv(tile, Wc,    WdbcT + (size_t)512 * 256,   256, 256, (uu - 128) & 7, (uu - 128) >> 3, t);
        else if (uu < 224) tconv(tile, W_out, W_outT,                      256, 128, (uu - 192) & 7, (uu - 192) >> 3, t);
        return;
    }

    // ---- GEMM role ----
    __shared__ short As[64][136];
    __shared__ short Bs[64][136];
    f32x4 acc[4] = {};
    const int w = t >> 6, lane = t & 63;
    const int srow = t >> 2, sseg = t & 3;
    const int frow = lane & 15, fk = (lane >> 4) << 3;
    const int r0 = blockIdx.y * 64, n0 = blockIdx.x * 64;

    {
        const float* ap = x + (size_t)(r0 + srow) * DM + sseg * 32;
        short tmp[32];
#pragma unroll
        for (int j = 0; j < 8; ++j) {
            float4 f = *(const float4*)(ap + j * 4);
            tmp[j * 4 + 0] = f2bf(f.x); tmp[j * 4 + 1] = f2bf(f.y);
            tmp[j * 4 + 2] = f2bf(f.z); tmp[j * 4 + 3] = f2bf(f.w);
        }
#pragma unroll
        for (int m = 0; m < 4; ++m)
            *(bf16x8*)&As[srow][sseg * 32 + m * 8] = *(bf16x8*)&tmp[m * 8];
    }
    {
#pragma unroll
        for (int i = 0; i < 32; i += 2) {
            const int k = sseg * 32 + i;
            float f0 = W_in[(size_t)k * 512 + n0 + srow];
            float f1 = W_in[(size_t)(k + 1) * 512 + n0 + srow];
            unsigned pk = (unsigned short)f2bf(f0) | ((unsigned)(unsigned short)f2bf(f1) << 16);
            *(unsigned*)&Bs[srow][k] = pk;
        }
    }
    __syncthreads();

#pragma unroll
    for (int kk = 0; kk < 128; kk += 32) {
        bf16x8 af = *(const bf16x8*)&As[w * 16 + frow][kk + fk];
#pragma unroll
        for (int ct = 0; ct < 4; ++ct) {
            bf16x8 bfr = *(const bf16x8*)&Bs[ct * 16 + frow][kk + fk];
            acc[ct] = __builtin_amdgcn_mfma_f32_16x16x32_bf16(af, bfr, acc[ct], 0, 0, 0);
        }
    }

    const int rr = r0 + w * 16 + (lane >> 4) * 4;
    const int c0 = n0 + (lane & 15);
#pragma unroll
    for (int ct = 0; ct < 4; ++ct) {
        const int c = c0 + ct * 16;
#pragma unroll
        for (int rg = 0; rg < 4; ++rg) {
            const float v = acc[ct][rg];
            const int r = rr + rg;
            if (c < DI) {
                xs[(size_t)r * DI + c]    = v;
                xs_bf[(size_t)r * DI + c] = f2bf(v);
            } else {
                sz[(size_t)r * DI + (c - DI)] = v / (1.f + __expf(-v));
            }
        }
    }
}

// ---------------------------------------------------------------------------
// kernel 2: dbc GEMM — 192 blocks x 512 thr, tile 64r x 128c, K=256.
// XCD mapping: blk&7 = f(b,c) -> writes for chunk (b,c) stay on the XCD
// that scans them.
// ---------------------------------------------------------------------------
__global__ __launch_bounds__(512) void k_dbc(
    const short* __restrict__ xs_bf, const short* __restrict__ WdbcT,
    const float* __restrict__ xs,
    float* __restrict__ dlt, float* __restrict__ u, float* __restrict__ cvv)
{
    __shared__ short As[64][72], Bs[128][72];
    const int blk = blockIdx.x, t = threadIdx.x;
    const int w8 = t >> 6, lane = t & 63;
    const int rf = w8 & 3, ch = w8 >> 2;
    const int frow = lane & 15, fk = (lane >> 4) << 3;
    const int xk = blk & 7, m = blk >> 3;          // m 0..23
    const int b  = xk & 3;
    const int c  = (xk >> 2) + 2 * (m / 6);        // 0..7
    const int bx = m % 6;
    const int r0 = b * 512 + c * 64, n0 = bx * 128;
    const int arow = t >> 3, ak = (t & 7) * 8;
    const int brow = t >> 2, bk = (t & 3) * 16;
    f32x4 acc[4] = {};

    for (int k0 = 0; k0 < DI; k0 += 64) {
        bf16x8 a0 = *(const bf16x8*)(xs_bf + (size_t)(r0 + arow) * DI + k0 + ak);
        bf16x8 b0 = *(const bf16x8*)(WdbcT + (size_t)(n0 + brow) * DI + k0 + bk);
        bf16x8 b1 = *(const bf16x8*)(WdbcT + (size_t)(n0 + brow) * DI + k0 + bk + 8);
        __syncthreads();
        *(bf16x8*)&As[arow][ak]     = a0;
        *(bf16x8*)&Bs[brow][bk]     = b0;
        *(bf16x8*)&Bs[brow][bk + 8] = b1;
        __syncthreads();
#pragma unroll
        for (int kk = 0; kk < 64; kk += 32) {
            bf16x8 af = *(const bf16x8*)&As[rf * 16 + frow][kk + fk];
#pragma unroll
            for (int ct = 0; ct < 4; ++ct) {
                bf16x8 bfr = *(const bf16x8*)&Bs[(ch * 4 + ct) * 16 + frow][kk + fk];
                acc[ct] = __builtin_amdgcn_mfma_f32_16x16x32_bf16(af, bfr, acc[ct], 0, 0, 0);
            }
        }
    }

    const int rr = r0 + rf * 16 + (lane >> 4) * 4;
    const int nbase = n0 + ch * 64;
    const int wsel = nbase >> 8;          // 0: delta, 1: B, 2: C
    const int nb = nbase & 255;
#pragma unroll
    for (int ct = 0; ct < 4; ++ct) {
        const int cc = nb + ct * 16 + (lane & 15);
#pragma unroll
        for (int rg = 0; rg < 4; ++rg) {
            const float v = acc[ct][rg];
            const size_t idx = (size_t)(rr + rg) * DI + cc;
            if (wsel == 0)      dlt[idx] = v;
            else if (wsel == 1) u[idx]   = v * xs[idx];   // Bv * xs
            else                cvv[idx] = v;
        }
    }
}

// ---------------------------------------------------------------------------
// kernel 3: scan pass 1 — chunk-local states, packed-f32, dbuf prefetch.
// 512 blocks, XCD mapping: blk&7 = f(b,c); g=blk>>3: c=(x>>2)+2*(g>>4),
// d0=(g&15)*16+w*4. Warms u rows for scan3 on the same XCD.
// ---------------------------------------------------------------------------
__global__ __launch_bounds__(256) void k_scan1(
    const float* __restrict__ dlt, const float* __restrict__ u,
    const float* __restrict__ Aa,
    float* __restrict__ tc, float* __restrict__ dsm)
{
    const int lane = threadIdx.x & 63;
    const int w    = threadIdx.x >> 6;
    const int blk  = blockIdx.x;
    const int xk = blk & 7, g = blk >> 3;
    const int b  = xk & 3;
    const int c  = (xk >> 2) + 2 * (g >> 4);
    const int d0 = (g & 15) * 16 + w * 4;

    __shared__ float4 dls4[4][LC];
    const size_t base = (size_t)b * LLEN * DI + (size_t)c * LC * DI;

    float4 dv = *(const float4*)(dlt + base + (size_t)lane * DI + d0);
    dls4[w][lane] = dv;
    float dsv[4] = { dv.x, dv.y, dv.z, dv.w };
#pragma unroll
    for (int dd = 0; dd < 4; ++dd) {
#pragma unroll
        for (int off = 32; off > 0; off >>= 1)
            dsv[dd] += __shfl_xor(dsv[dd], off);
    }

    const f32x2 one2 = {1.f, 1.f};
    f32x2 c1a[4], c1b[4], c2a[4], c2b[4];
#pragma unroll
    for (int dd = 0; dd < 4; ++dd) {
        float4 a = *(const float4*)(Aa + (size_t)(d0 + dd) * DS + lane * 4);
        c1a[dd] = (f32x2){a.x, a.y};
        c1b[dd] = (f32x2){a.z, a.w};
        c2a[dd] = (f32x2){0.5f * a.x * a.x, 0.5f * a.y * a.y};
        c2b[dd] = (f32x2){0.5f * a.z * a.z, 0.5f * a.w * a.w};
    }

    const float4* up = (const float4*)(u + base) + lane;
    f32x2 s0[4] = {}, s1[4] = {};
    float4 uA[4], uB[4];

#define S1_PRE(UB, G)                                                         \
    {                                                                         \
        _Pragma("unroll")                                                     \
        for (int i = 0; i < 4; ++i)                                           \
            UB[i] = up[(size_t)((G) * 4 + i) * 64];                           \
    }

#define S1_COMP(UB, G)                                                        \
    {                                                                         \
        _Pragma("unroll")                                                     \
        for (int i = 0; i < 4; ++i) {                                         \
            const float4 d4 = dls4[w][(G) * 4 + i];                           \
            const float dla[4] = { d4.x, d4.y, d4.z, d4.w };                  \
            const f32x2 u01 = (f32x2){UB[i].x, UB[i].y};                      \
            const f32x2 u23 = (f32x2){UB[i].z, UB[i].w};                      \
            _Pragma("unroll")                                                 \
            for (int dd = 0; dd < 4; ++dd) {                                  \
                const f32x2 dl2 = (f32x2){dla[dd], dla[dd]};                  \
                f32x2 e0 = FMA2(c2a[dd], dl2, c1a[dd]); e0 = FMA2(e0, dl2, one2); \
                f32x2 e1 = FMA2(c2b[dd], dl2, c1b[dd]); e1 = FMA2(e1, dl2, one2); \
                s0[dd] = FMA2(e0, s0[dd], dl2 * u01);                         \
                s1[dd] = FMA2(e1, s1[dd], dl2 * u23);                         \
            }                                                                 \
        }                                                                     \
    }

    S1_PRE(uA, 0)
    for (int g2 = 0; g2 < 8; ++g2) {
        S1_PRE(uB, g2 * 2 + 1)
        S1_COMP(uA, g2 * 2)
        if (g2 < 7) S1_PRE(uA, g2 * 2 + 2)
        S1_COMP(uB, g2 * 2 + 1)
    }
#undef S1_PRE
#undef S1_COMP

    const size_t rbb = ((size_t)(b * 256 + d0)) * NC + c;
#pragma unroll
    for (int dd = 0; dd < 4; ++dd) {
        *(float4*)(tc + (rbb + (size_t)dd * NC) * 256 + lane * 4) =
            make_float4(s0[dd][0], s0[dd][1], s1[dd][0], s1[dd][1]);
        if (lane == 0) dsm[rbb + dd * NC] = dsv[dd];
    }
}

// ---------------------------------------------------------------------------
// kernel 4: scan pass 3 — inline chunk-combine prologue + outputs.
// Same XCD mapping as scan1 (u/cv/dlt L2-local). Packed-f32; T stride 17.
// ---------------------------------------------------------------------------
__global__ __launch_bounds__(256) void k_scan3(
    const float* __restrict__ dlt, const float* __restrict__ u,
    const float* __restrict__ cvv, const float* __restrict__ Aa,
    const float* __restrict__ tc, const float* __restrict__ dsm,
    float* __restrict__ yv)
{
    const int lane = threadIdx.x & 63;
    const int w    = threadIdx.x >> 6;
    const int blk  = blockIdx.x;
    const int xk = blk & 7, g = blk >> 3;
    const int b  = xk & 3;
    const int c  = (xk >> 2) + 2 * (g >> 4);
    const int d0 = (g & 15) * 16 + w * 4;

    __shared__ float4 dls4[4][LC];
    __shared__ float T[4][LC][17];      // odd stride: conflict-free b32 R/W

    const size_t base = (size_t)b * LLEN * DI + (size_t)c * LC * DI;

    float4 dv = *(const float4*)(dlt + base + (size_t)lane * DI + d0);
    dls4[w][lane] = dv;

    const f32x2 one2 = {1.f, 1.f};
    f32x2 c1a[4], c1b[4], c2a[4], c2b[4];
#pragma unroll
    for (int dd = 0; dd < 4; ++dd) {
        float4 a = *(const float4*)(Aa + (size_t)(d0 + dd) * DS + lane * 4);
        c1a[dd] = (f32x2){a.x, a.y};
        c1b[dd] = (f32x2){a.z, a.w};
        c2a[dd] = (f32x2){0.5f * a.x * a.x, 0.5f * a.y * a.y};
        c2b[dd] = (f32x2){0.5f * a.z * a.z, 0.5f * a.w * a.w};
    }

    // ---- inline combine: s = s_init[c] from chunks 0..c-1 ----
    f32x2 s0[4] = {}, s1[4] = {};
    for (int cc = 0; cc < c; ++cc) {
#pragma unroll
        for (int dd = 0; dd < 4; ++dd) {
            const size_t rbd = ((size_t)(b * 256 + d0 + dd)) * NC + cc;
            const float4 Tt = *(const float4*)(tc + rbd * 256 + lane * 4);
            const float  Dc = dsm[rbd] * LOG2E;
            s0[dd][0] = exp2f(c1a[dd][0] * Dc) * s0[dd][0] + Tt.x;
            s0[dd][1] = exp2f(c1a[dd][1] * Dc) * s0[dd][1] + Tt.y;
            s1[dd][0] = exp2f(c1b[dd][0] * Dc) * s1[dd][0] + Tt.z;
            s1[dd][1] = exp2f(c1b[dd][1] * Dc) * s1[dd][1] + Tt.w;
        }
    }

    const float4* up = (const float4*)(u + base) + lane;
    const float4* cp = (const float4*)(cvv + base) + lane;
    float* yb = yv + base;

    const int col = lane & 15, seg = lane >> 4;
    float4 uA[4], cA[4], uB[4], cB[4];

#define S3_PRE(UB, CB, G)                                                     \
    {                                                                         \
        _Pragma("unroll")                                                     \
        for (int i = 0; i < 4; ++i) {                                         \
            UB[i] = up[(size_t)((G) * 4 + i) * 64];                           \
            CB[i] = cp[(size_t)((G) * 4 + i) * 64];                           \
        }                                                                     \
    }

#define S3_COMP(UB, CB, G)                                                    \
    {                                                                         \
        _Pragma("unroll")                                                     \
        for (int i = 0; i < 4; ++i) {                                         \
            const float4 d4 = dls4[w][(G) * 4 + i];                           \
            const float dla[4] = { d4.x, d4.y, d4.z, d4.w };                  \
            const f32x2 u01 = (f32x2){UB[i].x, UB[i].y};                      \
            const f32x2 u23 = (f32x2){UB[i].z, UB[i].w};                      \
            const f32x2 c01 = (f32x2){CB[i].x, CB[i].y};                      \
            const f32x2 c23 = (f32x2){CB[i].z, CB[i].w};                      \
            _Pragma("unroll")                                                 \
            for (int dd = 0; dd < 4; ++dd) {                                  \
                const f32x2 dl2 = (f32x2){dla[dd], dla[dd]};                  \
                f32x2 e0 = FMA2(c2a[dd], dl2, c1a[dd]); e0 = FMA2(e0, dl2, one2); \
                f32x2 e1 = FMA2(c2b[dd], dl2, c1b[dd]); e1 = FMA2(e1, dl2, one2); \
                s0[dd] = FMA2(e0, s0[dd], dl2 * u01);                         \
                s1[dd] = FMA2(e1, s1[dd], dl2 * u23);                         \
                f32x2 q = s0[dd] * c01;                                       \
                q = FMA2(s1[dd], c23, q);                                     \
                T[w][lane][dd * 4 + i] = q[0] + q[1];                         \
            }                                                                 \
        }                                                                     \
        float sm = 0.f;                                                       \
        _Pragma("unroll")                                                     \
        for (int rr2 = 0; rr2 < 16; ++rr2)                                    \
            sm += T[w][seg * 16 + rr2][col];                                  \
        sm += __shfl_xor(sm, 16);                                             \
        sm += __shfl_xor(sm, 32);                                             \
        if (lane < 16)                                                        \
            yb[(size_t)((G) * 4 + (col & 3)) * DI + d0 + (col >> 2)] = sm;    \
    }

    S3_PRE(uA, cA, 0)
    for (int g2 = 0; g2 < 8; ++g2) {
        S3_PRE(uB, cB, g2 * 2 + 1)
        S3_COMP(uA, cA, g2 * 2)
        if (g2 < 7) S3_PRE(uA, cA, g2 * 2 + 2)
        S3_COMP(uB, cB, g2 * 2 + 1)
    }
#undef S3_PRE
#undef S3_COMP
}

// ---------------------------------------------------------------------------
// kernel 5: out GEMM (MFMA) — 64 blocks x 256 thr, XCD-mapped to scan3's yv.
// ---------------------------------------------------------------------------
__global__ __launch_bounds__(256) void k_out_mfma(
    const float* __restrict__ y, const float* __restrict__ szp,
    const short* __restrict__ W_outT, float* __restrict__ out)
{
    __shared__ short As[64][72], Bs[64][72];
    f32x4 acc[4] = {};
    const int tid  = threadIdx.x;
    const int blk  = blockIdx.x;
    const int w    = tid >> 6, lane = tid & 63;
    const int srow = tid >> 2, sseg = tid & 3;
    const int frow = lane & 15, fk = (lane >> 4) << 3;
    const int xk = blk & 7, m = blk >> 3;          // m 0..7
    const int b  = xk & 3;
    const int c  = (xk >> 2) + 2 * (m >> 1);
    const int r0 = b * 512 + c * 64;
    const int n0 = (m & 1) * 64;

    for (int k0 = 0; k0 < DI; k0 += 64) {
        const size_t aoff = (size_t)(r0 + srow) * DI + k0 + sseg * 16;
        float4 y0 = *(const float4*)(y + aoff);
        float4 y1 = *(const float4*)(y + aoff + 4);
        float4 y2 = *(const float4*)(y + aoff + 8);
        float4 y3 = *(const float4*)(y + aoff + 12);
        float4 s0 = *(const float4*)(szp + aoff);
        float4 s1 = *(const float4*)(szp + aoff + 4);
        float4 s2 = *(const float4*)(szp + aoff + 8);
        float4 s3 = *(const float4*)(szp + aoff + 12);
        const short* bg = W_outT + (size_t)(n0 + srow) * DI + k0 + sseg * 16;
        bf16x8 b0 = *(const bf16x8*)bg;
        bf16x8 b1 = *(const bf16x8*)(bg + 8);
        bf16x8 a0, a1;
        a0[0] = f2bf(y0.x * s0.x); a0[1] = f2bf(y0.y * s0.y);
        a0[2] = f2bf(y0.z * s0.z); a0[3] = f2bf(y0.w * s0.w);
        a0[4] = f2bf(y1.x * s1.x); a0[5] = f2bf(y1.y * s1.y);
        a0[6] = f2bf(y1.z * s1.z); a0[7] = f2bf(y1.w * s1.w);
        a1[0] = f2bf(y2.x * s2.x); a1[1] = f2bf(y2.y * s2.y);
        a1[2] = f2bf(y2.z * s2.z); a1[3] = f2bf(y2.w * s2.w);
        a1[4] = f2bf(y3.x * s3.x); a1[5] = f2bf(y3.y * s3.y);
        a1[6] = f2bf(y3.z * s3.z); a1[7] = f2bf(y3.w * s3.w);
        __syncthreads();
        *(bf16x8*)&As[srow][sseg * 16]     = a0;
        *(bf16x8*)&As[srow][sseg * 16 + 8] = a1;
        *(bf16x8*)&Bs[srow][sseg * 16]     = b0;
        *(bf16x8*)&Bs[srow][sseg * 16 + 8] = b1;
        __syncthreads();
#pragma unroll
        for (int kk = 0; kk < 64; kk += 32) {
            bf16x8 af = *(const bf16x8*)&As[w * 16 + frow][kk + fk];
#pragma unroll
            for (int ct = 0; ct < 4; ++ct) {
                bf16x8 bfr = *(const bf16x8*)&Bs[ct * 16 + frow][kk + fk];
                acc[ct] = __builtin_amdgcn_mfma_f32_16x16x32_bf16(af, bfr, acc[ct], 0, 0, 0);
            }
        }
    }

    const int rr = r0 + w * 16 + (lane >> 4) * 4;
    const int c0 = n0 + (lane & 15);
#pragma unroll
    for (int ct = 0; ct < 4; ++ct) {
        const int cc = c0 + ct * 16;
#pragma unroll
        for (int rg = 0; rg < 4; ++rg)
            out[(size_t)(rr + rg) * DM + cc] = acc[ct][rg];
    }
}

// ---------------------------------------------------------------------------
extern "C" void kernel_launch(void* const* d_in, const int* in_sizes, int n_in,
                              void* d_out, int out_size, void* d_ws, size_t ws_size,
                              hipStream_t stream)
{
    const float* x       = (const float*)d_in[0];
    const float* W_in    = (const float*)d_in[1];
    const float* W_delta = (const float*)d_in[2];
    const float* W_B     = (const float*)d_in[3];
    const float* W_C     = (const float*)d_in[4];
    const float* W_out   = (const float*)d_in[5];
    const float* A       = (const float*)d_in[6];
    // d_in[7] = D, unused by the reference scan

    float* out = (float*)d_out;
    float* ws  = (float*)d_ws;

    const size_t S = (size_t)MROWS * DI;   // 524288 floats per plane (2 MB)
    float* xs  = ws;
    float* sz  = ws + S;
    float* dlt = ws + 2 * S;
    float* u   = ws + 3 * S;
    float* cv  = ws + 4 * S;
    float* yv  = ws + 5 * S;
    float* tc  = ws + 6 * S;                              // 1024*8*256 = 8 MB
    float* dsm = tc + (size_t)1024 * NC * 256;            // 8192 floats

    short* xs_bf  = (short*)(dsm + (size_t)1024 * NC);    // 2048*256
    short* WdbcT  = xs_bf + (size_t)MROWS * DI;           // 768*256
    short* W_outT = WdbcT + (size_t)768 * DI;             // 128*256

    k_proj_mfma<<<dim3(15, 32), 256, 0, stream>>>(x, W_in, W_delta, W_B, W_C, W_out,
                                                  xs, xs_bf, sz, WdbcT, W_outT);
    k_dbc      <<<dim3(192), 512, 0, stream>>>(xs_bf, WdbcT, xs, dlt, u, cv);
    k_scan1    <<<dim3(512), 256, 0, stream>>>(dlt, u, A, tc, dsm);
    k_scan3    <<<dim3(512), 256, 0, stream>>>(dlt, u, cv, A, tc, dsm, yv);
    k_out_mfma <<<dim3(64), 256, 0, stream>>>(yv, sz, W_outT, out);
}